// Round 1
// baseline (134.177 us; speedup 1.0000x reference)
//
#include <hip/hip_runtime.h>

// YOLO-v1 style loss on MI355X (gfx950).
// Inputs: d_in[0] = output (BATCH*S*S*30 fp32), d_in[1] = target (same).
// Outputs: d_out[0..2] = (loss, sum_iou, acc) as fp32.
//
// R3 post-mortem: LDS-staged version ran 41us at 2.35 TB/s effective.
// Counters: Occupancy 16% (62KB LDS -> 2 blocks/CU), VALUBusy 16%,
// 175K LDS bank conflicts. load->sync->compute->sync alternates memory
// and VALU phases with no overlap partner -> latency-bound, 2.7x off the
// 15.3us BW floor.
// R4: drop LDS entirely. One thread per CELL PAIR: 2 cells = 240 B and
// 240 % 16 == 0, so every pair base is 16B-aligned -> 15+15 float4 direct
// loads into registers, zero LDS, zero barriers. 64-thread (single-wave)
// blocks, 3136 blocks -> fine-grained scheduling, wave-level reduce only.

#define NACC 8

__device__ __forceinline__ float wave_reduce_sum(float v) {
    #pragma unroll
    for (int off = 32; off > 0; off >>= 1)
        v += __shfl_down(v, off, 64);
    return v;
}

// Per-cell loss contributions. o/t point at 30 consecutive floats held in
// registers (all indices compile-time constant after inlining -> no scratch).
__device__ __forceinline__ void cell_loss(const float* __restrict__ o,
                                          const float* __restrict__ t,
                                          float v[NACC]) {
    const float m = (t[4] > 0.f) ? 1.f : 0.f;

    const float txc = t[0] / 7.f, tyc = t[1] / 7.f;
    const float tx0 = txc - 0.5f * t[2], ty0 = tyc - 0.5f * t[3];
    const float tx1 = txc + 0.5f * t[2], ty1 = tyc + 0.5f * t[3];
    const float at  = (tx1 - tx0) * (ty1 - ty0);

    float iou[2];
    #pragma unroll
    for (int b = 0; b < 2; b++) {
        const float bx = o[5 * b + 0], by = o[5 * b + 1];
        const float bw = o[5 * b + 2], bh = o[5 * b + 3];
        const float xc = bx / 7.f, yc = by / 7.f;
        const float x0 = xc - 0.5f * bw, y0 = yc - 0.5f * bh;
        const float x1 = xc + 0.5f * bw, y1 = yc + 0.5f * bh;
        const float ap = (x1 - x0) * (y1 - y0);
        const float wi = fmaxf(fminf(x1, tx1) - fmaxf(x0, tx0), 0.f);
        const float hi = fmaxf(fminf(y1, ty1) - fmaxf(y0, ty0), 0.f);
        const float inter = wi * hi;
        iou[b] = inter / (ap + at - inter);
    }

    // argmax, first-max tie-break: responsible box is 1 only if STRICTLY greater
    const bool  r1      = iou[1] > iou[0];
    const float max_iou = fmaxf(iou[0], iou[1]);
    const float min_iou = fminf(iou[0], iou[1]);
    // explicit selects (no runtime-indexed register array -> no scratch)
    const float rb0 = r1 ? o[5] : o[0];
    const float rb1 = r1 ? o[6] : o[1];
    const float rb2 = r1 ? o[7] : o[2];
    const float rb3 = r1 ? o[8] : o[3];
    const float rb4 = r1 ? o[9] : o[4];
    const float nb4 = r1 ? o[4] : o[9];

    {
        const float dx = rb0 - t[0];
        const float dy = rb1 - t[1];
        const float dw = sqrtf(rb2) - sqrtf(t[2]);
        const float dh = sqrtf(rb3) - sqrtf(t[3]);
        v[1] += m * (dx * dx + dy * dy + dw * dw + dh * dh);
    }
    {
        const float d = rb4 - max_iou;
        v[2] += m * d * d;
    }
    v[3] += m * nb4 * nb4;
    {
        const float d0 = o[4] - t[4];
        const float d1 = o[9] - t[9];
        v[4] += (1.f - m) * (d0 * d0 + d1 * d1);
    }

    float cls_sum = 0.f;
    int   oarg = 0, targ = 0;
    float obest = o[10], tbest = t[10];
    #pragma unroll
    for (int c = 0; c < 20; c++) {
        const float oc = o[10 + c], tc = t[10 + c];
        const float d = oc - tc;
        cls_sum += d * d;
        if (oc > obest) { obest = oc; oarg = c; }
        if (tc > tbest) { tbest = tc; targ = c; }
    }
    v[5] += m * cls_sum;
    v[6] += m * min_iou;
    v[7] += (m > 0.f && oarg == targ) ? 1.f : 0.f;
    v[0] += m;
}

__global__ __launch_bounds__(64) void yolo_loss_kernel(
        const float* __restrict__ out,
        const float* __restrict__ tgt,
        float* __restrict__ partials, int N) {
    const int nPairs = N >> 1;
    const int idx = blockIdx.x * 64 + threadIdx.x;

    float v[NACC];
    #pragma unroll
    for (int k = 0; k < NACC; k++) v[k] = 0.f;

    if (idx < nPairs) {
        // pair base byte offset = idx*240, divisible by 16 -> float4 legal
        const float4* a4 = (const float4*)(out) + (size_t)idx * 15;
        const float4* b4 = (const float4*)(tgt) + (size_t)idx * 15;
        float o[60], t[60];
        #pragma unroll
        for (int k = 0; k < 15; k++) {
            const float4 x = a4[k];
            o[4 * k + 0] = x.x; o[4 * k + 1] = x.y;
            o[4 * k + 2] = x.z; o[4 * k + 3] = x.w;
        }
        #pragma unroll
        for (int k = 0; k < 15; k++) {
            const float4 y = b4[k];
            t[4 * k + 0] = y.x; t[4 * k + 1] = y.y;
            t[4 * k + 2] = y.z; t[4 * k + 3] = y.w;
        }
        cell_loss(o, t, v);
        cell_loss(o + 30, t + 30, v);
    } else if ((N & 1) && idx == nPairs) {
        // odd-N tail: last single cell, 8B-aligned -> float2 loads
        float o[30], t[30];
        const float2* a2 = (const float2*)(out + (size_t)(N - 1) * 30);
        const float2* b2 = (const float2*)(tgt + (size_t)(N - 1) * 30);
        #pragma unroll
        for (int k = 0; k < 15; k++) {
            const float2 x = a2[k];
            o[2 * k] = x.x; o[2 * k + 1] = x.y;
            const float2 y = b2[k];
            t[2 * k] = y.x; t[2 * k + 1] = y.y;
        }
        cell_loss(o, t, v);
    }

    // single-wave block: wave reduce IS the block reduce, no LDS, no barrier
    #pragma unroll
    for (int k = 0; k < NACC; k++) v[k] = wave_reduce_sum(v[k]);
    if (threadIdx.x == 0) {
        #pragma unroll
        for (int k = 0; k < NACC; k++)
            partials[(size_t)blockIdx.x * NACC + k] = v[k];
    }
}

__global__ __launch_bounds__(256) void yolo_finalize_kernel(
        const float* __restrict__ partials,
        float* __restrict__ res, int N, int rows) {
    __shared__ float sred[4][NACC];
    float v[NACC];
    #pragma unroll
    for (int k = 0; k < NACC; k++) v[k] = 0.f;

    for (int b = threadIdx.x; b < rows; b += 256) {
        #pragma unroll
        for (int k = 0; k < NACC; k++)
            v[k] += partials[(size_t)b * NACC + k];
    }

    const int lane = threadIdx.x & 63;
    const int wid  = threadIdx.x >> 6;
    #pragma unroll
    for (int k = 0; k < NACC; k++) v[k] = wave_reduce_sum(v[k]);
    if (lane == 0) {
        #pragma unroll
        for (int k = 0; k < NACC; k++) sred[wid][k] = v[k];
    }
    __syncthreads();
    if (threadIdx.x == 0) {
        float acc[NACC];
        #pragma unroll
        for (int k = 0; k < NACC; k++)
            acc[k] = sred[0][k] + sred[1][k] + sred[2][k] + sred[3][k];
        const float n_obj   = acc[0];
        const float n_noobj = (float)N - n_obj;
        const float contain     = acc[1] / (2.f * n_obj);
        const float obj_loss    = acc[2] / n_obj;
        const float not_contain = acc[3] / n_obj;
        const float noobj_loss  = acc[4] / (2.f * n_noobj);
        const float class_loss  = acc[5] / (n_obj * 20.f);
        res[0] = 5.f * contain + obj_loss
               + 0.5f * (noobj_loss + not_contain) + class_loss;
        res[1] = acc[6];
        res[2] = acc[7];
    }
}

extern "C" void kernel_launch(void* const* d_in, const int* in_sizes, int n_in,
                              void* d_out, int out_size, void* d_ws, size_t ws_size,
                              hipStream_t stream) {
    const float* out_p = (const float*)d_in[0];
    const float* tgt_p = (const float*)d_in[1];
    float* ws  = (float*)d_ws;   // blocks*NACC partial sums
    float* res = (float*)d_out;
    const int N = in_sizes[0] / 30;        // 8192*7*7 = 401408 cells
    const int nPairs  = N >> 1;
    const int workers = nPairs + (N & 1);
    int blocks = (workers + 63) / 64;      // 3136 for N=401408
    if (blocks < 1) blocks = 1;

    yolo_loss_kernel<<<blocks, 64, 0, stream>>>(out_p, tgt_p, ws, N);
    yolo_finalize_kernel<<<1, 256, 0, stream>>>(ws, res, N, blocks);
}

// Round 2
// 115.441 us; speedup vs baseline: 1.1623x; 1.1623x over previous
//
#include <hip/hip_runtime.h>

// YOLO-v1 style loss on MI355X (gfx950).
// Inputs: d_in[0] = output (BATCH*S*S*30 fp32), d_in[1] = target (same).
// Outputs: d_out[0..2] = (loss, sum_iou, acc) as fp32.
//
// R4 post-mortem: direct per-pair float4 loads have 240B lane stride ->
// 64 cache lines PER load instruction -> TA address-coalescing serializes
// (~8x issue inflation). 43us, VALUBusy 8%. AoS 120B records need LDS as
// the transposer.
// R3 post-mortem: LDS staging with __syncthreads() drains vmcnt(0) every
// tile -> load and compute phases strictly alternate. 41us.
// R5: LDS double-buffered pipeline (T3+T4 pattern): global_load_lds
// direct-to-LDS staging (coalesced 1KB/instr), raw s_barrier, counted
// s_waitcnt vmcnt(15) so the next tile's 61KB stays in flight across the
// barrier. 15 loads/wave exactly (extra A-round on waves 0-1, extra
// B-round on waves 2-3) so the counted wait is wave-uniform.

#define NACC 8
#define CELLS 256
#define TILE_FLOATS (CELLS * 30)        // 7680 floats = 30720 B per array
#define TILE_CHUNKS (TILE_FLOATS / 4)   // 1920 float4 chunks per array
#define GRID 256                        // 1 block/CU (LDS-capped), persistent

__device__ __forceinline__ float wave_reduce_sum(float v) {
    #pragma unroll
    for (int off = 32; off > 0; off >>= 1)
        v += __shfl_down(v, off, 64);
    return v;
}

__device__ __forceinline__ void gld16(const float4* g, float4* l) {
    __builtin_amdgcn_global_load_lds(
        (const __attribute__((address_space(1))) void*)g,
        (__attribute__((address_space(3))) void*)l, 16, 0, 0);
}

// Per-cell loss contributions; o/t are 30 floats with compile-time indices.
__device__ __forceinline__ void cell_loss(const float* __restrict__ o,
                                          const float* __restrict__ t,
                                          float v[NACC]) {
    const float m = (t[4] > 0.f) ? 1.f : 0.f;

    const float txc = t[0] / 7.f, tyc = t[1] / 7.f;
    const float tx0 = txc - 0.5f * t[2], ty0 = tyc - 0.5f * t[3];
    const float tx1 = txc + 0.5f * t[2], ty1 = tyc + 0.5f * t[3];
    const float at  = (tx1 - tx0) * (ty1 - ty0);

    float iou[2];
    #pragma unroll
    for (int b = 0; b < 2; b++) {
        const float bx = o[5 * b + 0], by = o[5 * b + 1];
        const float bw = o[5 * b + 2], bh = o[5 * b + 3];
        const float xc = bx / 7.f, yc = by / 7.f;
        const float x0 = xc - 0.5f * bw, y0 = yc - 0.5f * bh;
        const float x1 = xc + 0.5f * bw, y1 = yc + 0.5f * bh;
        const float ap = (x1 - x0) * (y1 - y0);
        const float wi = fmaxf(fminf(x1, tx1) - fmaxf(x0, tx0), 0.f);
        const float hi = fmaxf(fminf(y1, ty1) - fmaxf(y0, ty0), 0.f);
        const float inter = wi * hi;
        iou[b] = inter / (ap + at - inter);
    }

    // first-max tie-break: box 1 responsible only if STRICTLY greater
    const bool  r1      = iou[1] > iou[0];
    const float max_iou = fmaxf(iou[0], iou[1]);
    const float min_iou = fminf(iou[0], iou[1]);
    const float rb0 = r1 ? o[5] : o[0];
    const float rb1 = r1 ? o[6] : o[1];
    const float rb2 = r1 ? o[7] : o[2];
    const float rb3 = r1 ? o[8] : o[3];
    const float rb4 = r1 ? o[9] : o[4];
    const float nb4 = r1 ? o[4] : o[9];

    {
        const float dx = rb0 - t[0];
        const float dy = rb1 - t[1];
        const float dw = sqrtf(rb2) - sqrtf(t[2]);
        const float dh = sqrtf(rb3) - sqrtf(t[3]);
        v[1] += m * (dx * dx + dy * dy + dw * dw + dh * dh);
    }
    {
        const float d = rb4 - max_iou;
        v[2] += m * d * d;
    }
    v[3] += m * nb4 * nb4;
    {
        const float d0 = o[4] - t[4];
        const float d1 = o[9] - t[9];
        v[4] += (1.f - m) * (d0 * d0 + d1 * d1);
    }

    float cls_sum = 0.f;
    int   oarg = 0, targ = 0;
    float obest = o[10], tbest = t[10];
    #pragma unroll
    for (int c = 0; c < 20; c++) {
        const float oc = o[10 + c], tc = t[10 + c];
        const float d = oc - tc;
        cls_sum += d * d;
        if (oc > obest) { obest = oc; oarg = c; }
        if (tc > tbest) { tbest = tc; targ = c; }
    }
    v[5] += m * cls_sum;
    v[6] += m * min_iou;
    v[7] += (m > 0.f && oarg == targ) ? 1.f : 0.f;
    v[0] += m;
}

__global__ __launch_bounds__(256) void yolo_loss_kernel(
        const float* __restrict__ out,
        const float* __restrict__ tgt,
        float* __restrict__ partials, int N) {
    __shared__ float sA[2][TILE_FLOATS];   // 61440 B
    __shared__ float sB[2][TILE_FLOATS];   // 61440 B  (total 122880 + sred)
    __shared__ float sred[4][NACC];

    const int tid = threadIdx.x;
    const int numFull = N / CELLS;

    float v[NACC];
    #pragma unroll
    for (int k = 0; k < NACC; k++) v[k] = 0.f;

    // issue 15 global_load_lds per WAVE (uniform -> constant vmcnt works):
    // 1920 chunks/array = 7 full rounds + 128; extra A-round -> waves 0,1;
    // extra B-round -> waves 2,3.
    auto stage = [&](int buf, int tile) {
        const float4* gA = (const float4*)(out + (size_t)tile * TILE_FLOATS);
        const float4* gB = (const float4*)(tgt + (size_t)tile * TILE_FLOATS);
        float4* lA = (float4*)sA[buf];
        float4* lB = (float4*)sB[buf];
        #pragma unroll
        for (int j = 0; j < 7; j++) {
            const int c = j * 256 + tid;
            gld16(gA + c, lA + c);
        }
        if (tid < 128) gld16(gA + 1792 + tid, lA + 1792 + tid);
        #pragma unroll
        for (int j = 0; j < 7; j++) {
            const int c = j * 256 + tid;
            gld16(gB + c, lB + c);
        }
        if (tid >= 128) gld16(gB + 1792 + (tid - 128), lB + 1792 + (tid - 128));
    };

    auto compute = [&](int buf) {
        // cell base = tid*120 B, 8B-aligned -> float2 LDS reads
        float o[30], t[30];
        const float2* a2 = (const float2*)(sA[buf] + tid * 30);
        const float2* b2 = (const float2*)(sB[buf] + tid * 30);
        #pragma unroll
        for (int k = 0; k < 15; k++) {
            const float2 xa = a2[k];
            o[2 * k] = xa.x; o[2 * k + 1] = xa.y;
            const float2 xb = b2[k];
            t[2 * k] = xb.x; t[2 * k + 1] = xb.y;
        }
        cell_loss(o, t, v);
    };

    int t = blockIdx.x;
    int cur = 0;
    if (t < numFull) {
        stage(0, t);
        for (;;) {
            const int tn = t + GRID;
            const bool more = (tn < numFull);
            if (more) {
                stage(cur ^ 1, tn);
                // wait current tile's loads (issued last iter) while the
                // next tile's 15/wave stay in flight across the barrier
                asm volatile("s_waitcnt vmcnt(15)" ::: "memory");
            } else {
                asm volatile("s_waitcnt vmcnt(0)" ::: "memory");
            }
            __builtin_amdgcn_s_barrier();   // all waves' stage(cur) complete
            compute(cur);
            if (!more) break;
            __builtin_amdgcn_s_barrier();   // all waves done reading buf cur
            cur ^= 1;                       // before it is re-staged next iter
            t = tn;
        }
    }

    // tail cells (N % CELLS != 0): block 0, direct float2 loads (tiny)
    const int rem = N - numFull * CELLS;
    if (rem > 0 && blockIdx.x == 0 && tid < rem) {
        float o[30], tt[30];
        const size_t cb = (size_t)(numFull * CELLS + tid) * 30;
        const float2* a2 = (const float2*)(out + cb);
        const float2* b2 = (const float2*)(tgt + cb);
        #pragma unroll
        for (int k = 0; k < 15; k++) {
            const float2 xa = a2[k];
            o[2 * k] = xa.x; o[2 * k + 1] = xa.y;
            const float2 xb = b2[k];
            tt[2 * k] = xb.x; tt[2 * k + 1] = xb.y;
        }
        cell_loss(o, tt, v);
    }

    // block reduce 8 sums -> one plain store set per block (no atomics)
    const int lane = tid & 63;
    const int wid  = tid >> 6;
    #pragma unroll
    for (int k = 0; k < NACC; k++) v[k] = wave_reduce_sum(v[k]);
    __syncthreads();
    if (lane == 0) {
        #pragma unroll
        for (int k = 0; k < NACC; k++) sred[wid][k] = v[k];
    }
    __syncthreads();
    if (tid < NACC) {
        const int k = tid;
        partials[(size_t)blockIdx.x * NACC + k] =
            sred[0][k] + sred[1][k] + sred[2][k] + sred[3][k];
    }
}

__global__ __launch_bounds__(256) void yolo_finalize_kernel(
        const float* __restrict__ partials,
        float* __restrict__ res, int N, int rows) {
    __shared__ float sred[4][NACC];
    float v[NACC];
    #pragma unroll
    for (int k = 0; k < NACC; k++) v[k] = 0.f;

    for (int b = threadIdx.x; b < rows; b += 256) {
        #pragma unroll
        for (int k = 0; k < NACC; k++)
            v[k] += partials[(size_t)b * NACC + k];
    }

    const int lane = threadIdx.x & 63;
    const int wid  = threadIdx.x >> 6;
    #pragma unroll
    for (int k = 0; k < NACC; k++) v[k] = wave_reduce_sum(v[k]);
    if (lane == 0) {
        #pragma unroll
        for (int k = 0; k < NACC; k++) sred[wid][k] = v[k];
    }
    __syncthreads();
    if (threadIdx.x == 0) {
        float acc[NACC];
        #pragma unroll
        for (int k = 0; k < NACC; k++)
            acc[k] = sred[0][k] + sred[1][k] + sred[2][k] + sred[3][k];
        const float n_obj   = acc[0];
        const float n_noobj = (float)N - n_obj;
        const float contain     = acc[1] / (2.f * n_obj);
        const float obj_loss    = acc[2] / n_obj;
        const float not_contain = acc[3] / n_obj;
        const float noobj_loss  = acc[4] / (2.f * n_noobj);
        const float class_loss  = acc[5] / (n_obj * 20.f);
        res[0] = 5.f * contain + obj_loss
               + 0.5f * (noobj_loss + not_contain) + class_loss;
        res[1] = acc[6];
        res[2] = acc[7];
    }
}

extern "C" void kernel_launch(void* const* d_in, const int* in_sizes, int n_in,
                              void* d_out, int out_size, void* d_ws, size_t ws_size,
                              hipStream_t stream) {
    const float* out_p = (const float*)d_in[0];
    const float* tgt_p = (const float*)d_in[1];
    float* ws  = (float*)d_ws;   // GRID*NACC partial sums
    float* res = (float*)d_out;
    const int N = in_sizes[0] / 30;  // 8192*7*7 = 401408 cells

    yolo_loss_kernel<<<GRID, 256, 0, stream>>>(out_p, tgt_p, ws, N);
    yolo_finalize_kernel<<<1, 256, 0, stream>>>(ws, res, N, GRID);
}